// Round 20
// baseline (119.568 us; speedup 1.0000x reference)
//
#include <hip/hip_runtime.h>
#include <math.h>

#define NOSC 2048
#define NB 16
#define DT 0.1f
#define M_TOT (NB * NOSC)    // 32768
#define KTP 2056             // padded LDS K row
#define NBLK 128

typedef __attribute__((ext_vector_type(8))) short bf16x8;
typedef __attribute__((ext_vector_type(4))) float f32x4;

__device__ __forceinline__ unsigned short f2bf(float x) {
    unsigned int u = __float_as_uint(x);
    u += 0x7FFFu + ((u >> 16) & 1u);          // round-to-nearest-even
    return (unsigned short)(u >> 16);
}
__device__ __forceinline__ float bf2f(unsigned short u) {
    return __uint_as_float(((unsigned int)u) << 16);
}

// Fragment-tiled R (verified r15/r19): sin idx(c,j) = (j>>3)*128 + c*8 + (j&7),
// cos at +M_TOT. Wave w's A-fragment chunk k is CONTIGUOUS at
// [w*2048 + k*512 + lane*8 .. +8) shorts; element e there is
// (c = lane&15, j = w*128 + (lane>>4)*8 + k*32 + e).
__device__ __forceinline__ int ridx(int c, int j) {
    return ((j >> 3) << 7) + (c << 3) + (j & 7);
}

// Fragment-tiled K: Kbt offset(bx, w, k, lane) = (((bx*16+w)*4+k)<<9)+(lane<<3).
// Stored once in step 0 from the LDS tile; steps 1-9 read dense 1 KB/wave.

// ws layout: Kbt[8 MB] | RA (128 KB) | RB (128 KB) | accum[32] f32 | ticket u32

// ---------- fused step (r19 engine; FIRST also does init, FINAL also coherence)
// 128 blocks x 1024 thr (16 waves). Block owns i in [bx*16, +16), all 16
// batches. Wave w = k-sixteenth: dual 4-deep MFMA chains (sin/cos share B).
// FIRST: A-fragments from sincosf(theta_in) (== init values); K tile f32->bf16
//        via LDS, written through to Kbt densely; zeroes accum/ticket.
// FINAL: atan2 wrap + fused coherence (shfl reduce + atomics + ticket finalize).
template <bool FIRST, bool FINAL>
__global__ __launch_bounds__(1024, 4) void step_kernel(
    const float* __restrict__ theta_in,
    const float* __restrict__ Kmat,
    unsigned short* __restrict__ Kbt,
    const unsigned short* __restrict__ Rc,
    unsigned short* __restrict__ Rn,
    const float* __restrict__ omega,
    const float* __restrict__ kg,
    const float* __restrict__ mod,
    float* __restrict__ th,
    float* __restrict__ coh,
    float* __restrict__ accum,
    unsigned int* __restrict__ ticket)
{
    __shared__ float part[16][2][64][4];     // 32 KB
    __shared__ float coup[32][16];           // 2 KB

    const int t = threadIdx.x;
    const int lane = t & 63;
    const int w = t >> 6;
    const int i0 = blockIdx.x * 16;
    const int rl = lane & 15;
    const int kbase = w * 128 + ((lane >> 4) << 3);

    // ---- prefetch theta-update inputs (waves 0..3)
    float th_o = 0.0f, sin_i = 0.0f, cos_i = 0.0f, om_i = 0.0f;
    size_t o_upd = 0; int Lr = 0;
    if (t < 256) {
        const int b2 = t >> 4;
        const int il = t & 15;
        o_upd = (size_t)b2 * NOSC + i0 + il;
        Lr = ridx(b2, i0 + il);
        om_i = omega[i0 + il];
        if constexpr (FIRST) {
            th_o = theta_in[o_upd];
            sincosf(th_o, &sin_i, &cos_i);
        } else {
            th_o = th[o_upd];
            sin_i = bf2f(Rc[Lr]);
            cos_i = bf2f(Rc[M_TOT + Lr]);
        }
    }
    const float scale = kg[0] * (1.0f + mod[0]) * (1.0f / (float)NOSC);

    bf16x8 as[4], ac[4], bb[4];
    unsigned short* __restrict__ kf =
        Kbt + (((size_t)blockIdx.x * 16 + w) << 11) + (lane << 3);

    if constexpr (FIRST) {
        if (blockIdx.x == 0) {                       // zero coherence accum
            if (t < 32) accum[t] = 0.0f;
            if (t == 32) *ticket = 0u;
        }
        // ---- B: convert this block's K tile (16 rows, 128 KB fp32) via LDS
        __shared__ unsigned short Kt[16][KTP];       // 64.25 KB (step 0 only)
        const float4* __restrict__ src =
            reinterpret_cast<const float4*>(Kmat + (size_t)i0 * NOSC);
#pragma unroll
        for (int p = 0; p < 8; ++p) {
            const int q = t + p * 1024;              // float4 index 0..8191
            float4 v = src[q];
            ushort4 u = {f2bf(v.x), f2bf(v.y), f2bf(v.z), f2bf(v.w)};
            *reinterpret_cast<ushort4*>(&Kt[q >> 9][(q & 511) * 4]) = u;
        }
        __syncthreads();
#pragma unroll
        for (int k = 0; k < 4; ++k) {
            bb[k] = *reinterpret_cast<const bf16x8*>(&Kt[rl][kbase + k * 32]);
            *reinterpret_cast<bf16x8*>(kf + (k << 9)) = bb[k];   // dense write-through
        }
        // ---- A: sincosf of theta_in directly (c = rl, j = kbase + k*32 + e)
        const float* __restrict__ tp = theta_in + (size_t)rl * NOSC + kbase;
#pragma unroll
        for (int k = 0; k < 4; ++k) {
            bf16x8 a_s, a_c;
#pragma unroll
            for (int e = 0; e < 8; ++e) {
                float s, c;
                sincosf(tp[k * 32 + e], &s, &c);
                a_s[e] = (short)f2bf(s);
                a_c[e] = (short)f2bf(c);
            }
            as[k] = a_s;
            ac[k] = a_c;
        }
    } else {
#pragma unroll
        for (int k = 0; k < 4; ++k)
            bb[k] = *reinterpret_cast<const bf16x8*>(kf + (k << 9));
        const unsigned short* __restrict__ pa = Rc + (w << 11) + (lane << 3);
#pragma unroll
        for (int k = 0; k < 4; ++k) {
            as[k] = *reinterpret_cast<const bf16x8*>(pa + (k << 9));
            ac[k] = *reinterpret_cast<const bf16x8*>(pa + M_TOT + (k << 9));
        }
    }

    f32x4 acc_s = {0.0f, 0.0f, 0.0f, 0.0f};
    f32x4 acc_c = {0.0f, 0.0f, 0.0f, 0.0f};
#pragma unroll
    for (int k = 0; k < 4; ++k) {
        acc_s = __builtin_amdgcn_mfma_f32_16x16x32_bf16(as[k], bb[k], acc_s, 0, 0, 0);
        acc_c = __builtin_amdgcn_mfma_f32_16x16x32_bf16(ac[k], bb[k], acc_c, 0, 0, 0);
    }
    *reinterpret_cast<f32x4*>(&part[w][0][lane][0]) = acc_s;
    *reinterpret_cast<f32x4*>(&part[w][1][lane][0]) = acc_c;
    __syncthreads();

    // ---- reduce 16 k-partials: cell (c, il), c = half*16 + (ln>>4)*4 + rg
    if (t < 512) {
        const int c = t >> 4, il = t & 15;
        const int half = c >> 4, cl = c & 15;
        const int ln = ((cl >> 2) << 4) | il, rg = cl & 3;
        float s = 0.0f;
#pragma unroll
        for (int q = 0; q < 16; ++q) s += part[q][half][ln][rg];
        coup[c][il] = s;
    }
    __syncthreads();

    // ---- theta update for this block's 256 (b, i)
    if (t < 256) {
        const int b2 = t >> 4;
        const int il = t & 15;
        const float aS = coup[b2][il];
        const float aC = coup[16 + b2][il];
        float nt = th_o + DT * (om_i + scale * (cos_i * aS - sin_i * aC));
        float ws, wc;
        sincosf(nt, &ws, &wc);
        if constexpr (FINAL) {
            th[o_upd] = atan2f(ws, wc);        // final wrap to (-pi, pi]
            // fused coherence: reduce over il (xor masks < 16 stay in group)
#pragma unroll
            for (int m = 1; m < 16; m <<= 1) {
                ws += __shfl_xor(ws, m);
                wc += __shfl_xor(wc, m);
            }
            if (il == 0) {
                atomicAdd(&accum[b2], ws);
                atomicAdd(&accum[16 + b2], wc);
            }
        } else {
            // wrap only shifts by 2*pi*k -> sin/cos unchanged; defer atan2
            th[o_upd] = nt;
            float sn = __shfl_down(ws, 1), cn = __shfl_down(wc, 1);
            if ((il & 1) == 0) {
                *reinterpret_cast<unsigned int*>(Rn + Lr) =
                    (unsigned)f2bf(ws) | ((unsigned)f2bf(sn) << 16);
                *reinterpret_cast<unsigned int*>(Rn + M_TOT + Lr) =
                    (unsigned)f2bf(wc) | ((unsigned)f2bf(cn) << 16);
            }
        }
    }

    if constexpr (FINAL) {
        __syncthreads();
        __threadfence();
        if (t == 0) {
            const unsigned int tk = atomicAdd(ticket, 1u);
            if (tk == NBLK - 1) {              // last block finalizes
                for (int b = 0; b < NB; ++b) {
                    float ss = atomicAdd(&accum[b], 0.0f) * (1.0f / (float)NOSC);
                    float cc = atomicAdd(&accum[16 + b], 0.0f) * (1.0f / (float)NOSC);
                    coh[b] = sqrtf(ss * ss + cc * cc);
                }
            }
        }
    }
}

extern "C" void kernel_launch(void* const* d_in, const int* in_sizes, int n_in,
                              void* d_out, int out_size, void* d_ws, size_t ws_size,
                              hipStream_t stream) {
    const float* theta_in = (const float*)d_in[0];
    const float* Kmat     = (const float*)d_in[1];
    const float* omega    = (const float*)d_in[2];
    const float* kg       = (const float*)d_in[3];
    const float* mod      = (const float*)d_in[4];

    float* th  = (float*)d_out;               // [NB][NOSC] final theta
    float* coh = (float*)d_out + M_TOT;       // [NB]

    unsigned short* Kbt = (unsigned short*)d_ws;                      // 8 MB
    unsigned short* RA  = Kbt + (size_t)NOSC * NOSC;                  // 128 KB
    unsigned short* RB  = RA + 2 * M_TOT;                             // 128 KB
    float* accum = (float*)(RB + 2 * M_TOT);                          // 32 f32
    unsigned int* ticket = (unsigned int*)(accum + 32);

    // 10 dispatches total. Parity: step s even reads RA writes RB, odd reads
    // RB writes RA (step 0 ignores Rc; step 9 ignores Rn).
    for (int s = 0; s < 10; ++s) {
        const unsigned short* rc = (s & 1) ? RB : RA;
        unsigned short* rn = (s & 1) ? RA : RB;
        if (s == 0)
            step_kernel<true, false><<<NBLK, 1024, 0, stream>>>(
                theta_in, Kmat, Kbt, rc, rn, omega, kg, mod, th, coh, accum, ticket);
        else if (s < 9)
            step_kernel<false, false><<<NBLK, 1024, 0, stream>>>(
                theta_in, Kmat, Kbt, rc, rn, omega, kg, mod, th, coh, accum, ticket);
        else
            step_kernel<false, true><<<NBLK, 1024, 0, stream>>>(
                theta_in, Kmat, Kbt, rc, rn, omega, kg, mod, th, coh, accum, ticket);
    }
}

// Round 21
// 100.961 us; speedup vs baseline: 1.1843x; 1.1843x over previous
//
#include <hip/hip_runtime.h>
#include <math.h>

#define NOSC 2048
#define NB 16
#define DT 0.1f
#define M_TOT (NB * NOSC)    // 32768
#define KTP 2056             // padded LDS K row
#define NBLK 128

typedef __attribute__((ext_vector_type(8))) short bf16x8;
typedef __attribute__((ext_vector_type(4))) float f32x4;

__device__ __forceinline__ unsigned short f2bf(float x) {
    unsigned int u = __float_as_uint(x);
    u += 0x7FFFu + ((u >> 16) & 1u);          // round-to-nearest-even
    return (unsigned short)(u >> 16);
}
__device__ __forceinline__ float bf2f(unsigned short u) {
    return __uint_as_float(((unsigned int)u) << 16);
}

// Fragment-tiled R (verified r15/r19): sin idx(c,j) = (j>>3)*128 + c*8 + (j&7),
// cos at +M_TOT. Wave w's A-fragment chunk k is CONTIGUOUS at
// [w*2048 + k*512 + lane*8 .. +8) shorts.
__device__ __forceinline__ int ridx(int c, int j) {
    return ((j >> 3) << 7) + (c << 3) + (j & 7);
}

// Fragment-tiled K: Kbt offset(bx, w, k, lane) = (((bx*16+w)*4+k)<<9)+(lane<<3).
// Stored once in step 0 from the LDS tile; steps 1-9 read dense 1 KB/wave.

// ws layout: Kbt[8 MB] | RA (128 KB) | RB (128 KB) | accum[32] f32 | ticket u32

// ---------- init: copy theta, build tiled R0, zero accum/ticket ----------
// (kept separate on purpose: fusing into step 0 forces 128x redundant sincosf
//  — measured 59 us in r20)
__global__ void init_kernel(const float* __restrict__ th_in,
                            float* __restrict__ th,
                            unsigned short* __restrict__ R0,
                            float* __restrict__ accum,
                            unsigned int* __restrict__ ticket) {
    const int idx = blockIdx.x * 256 + threadIdx.x;   // 0..8191
    const int o4 = idx * 4;
    float4 v = *reinterpret_cast<const float4*>(th_in + o4);
    *reinterpret_cast<float4*>(th + o4) = v;
    const int b = o4 >> 11;
    const int j = o4 & (NOSC - 1);                    // j % 4 == 0
    float s0, c0, s1, c1, s2, c2, s3, c3;
    sincosf(v.x, &s0, &c0); sincosf(v.y, &s1, &c1);
    sincosf(v.z, &s2, &c2); sincosf(v.w, &s3, &c3);
    const int L = ridx(b, j);                         // 4 elems stay in-block
    ushort4 us = {f2bf(s0), f2bf(s1), f2bf(s2), f2bf(s3)};
    ushort4 uc = {f2bf(c0), f2bf(c1), f2bf(c2), f2bf(c3)};
    *reinterpret_cast<ushort4*>(R0 + L) = us;
    *reinterpret_cast<ushort4*>(R0 + M_TOT + L) = uc;
    if (blockIdx.x == 0) {
        if (threadIdx.x < 32) accum[threadIdx.x] = 0.0f;
        if (threadIdx.x == 32) *ticket = 0u;
    }
}

// ---------- fused step (r19 engine; FINAL adds fused coherence) ----------
// 128 blocks x 1024 thr (16 waves). Block owns i in [bx*16, +16), all 16
// batches. Wave w = k-sixteenth: dual 4-deep MFMA chains (sin/cos share B).
// FIRST: K tile f32->bf16 via LDS; each wave writes its B fragments DENSELY
// to Kbt. Else: B = dense Kbt loads.
// FINAL: atan2 wrap + coherence (shfl reduce + atomics + ticket finalize).
template <bool FIRST, bool FINAL>
__global__ __launch_bounds__(1024, 4) void step_kernel(
    const float* __restrict__ Kmat,
    unsigned short* __restrict__ Kbt,
    const unsigned short* __restrict__ Rc,
    unsigned short* __restrict__ Rn,
    const float* __restrict__ omega,
    const float* __restrict__ kg,
    const float* __restrict__ mod,
    float* __restrict__ th,
    float* __restrict__ coh,
    float* __restrict__ accum,
    unsigned int* __restrict__ ticket)
{
    __shared__ float part[16][2][64][4];     // 32 KB
    __shared__ float coup[32][16];           // 2 KB

    const int t = threadIdx.x;
    const int lane = t & 63;
    const int w = t >> 6;
    const int i0 = blockIdx.x * 16;
    const int rl = lane & 15;
    const int kbase = w * 128 + ((lane >> 4) << 3);

    // ---- prefetch theta-update inputs (waves 0..3)
    float th_o = 0.0f, sin_i = 0.0f, cos_i = 0.0f, om_i = 0.0f;
    size_t o_upd = 0; int Lr = 0;
    if (t < 256) {
        const int b2 = t >> 4;
        const int il = t & 15;
        o_upd = (size_t)b2 * NOSC + i0 + il;
        Lr = ridx(b2, i0 + il);
        th_o = th[o_upd];
        sin_i = bf2f(Rc[Lr]);
        cos_i = bf2f(Rc[M_TOT + Lr]);
        om_i = omega[i0 + il];
    }
    const float scale = kg[0] * (1.0f + mod[0]) * (1.0f / (float)NOSC);

    // ---- B fragments
    bf16x8 as[4], ac[4], bb[4];
    unsigned short* __restrict__ kf =
        Kbt + (((size_t)blockIdx.x * 16 + w) << 11) + (lane << 3);
    if constexpr (FIRST) {
        __shared__ unsigned short Kt[16][KTP];       // 64.25 KB (step 0 only)
        const float4* __restrict__ src =
            reinterpret_cast<const float4*>(Kmat + (size_t)i0 * NOSC);
#pragma unroll
        for (int p = 0; p < 8; ++p) {
            const int q = t + p * 1024;              // float4 index 0..8191
            float4 v = src[q];
            ushort4 u = {f2bf(v.x), f2bf(v.y), f2bf(v.z), f2bf(v.w)};
            *reinterpret_cast<ushort4*>(&Kt[q >> 9][(q & 511) * 4]) = u;
        }
        __syncthreads();
#pragma unroll
        for (int k = 0; k < 4; ++k) {
            bb[k] = *reinterpret_cast<const bf16x8*>(&Kt[rl][kbase + k * 32]);
            // write-through in fragment-tiled order (dense 1 KB/wave stores)
            *reinterpret_cast<bf16x8*>(kf + (k << 9)) = bb[k];
        }
    } else {
#pragma unroll
        for (int k = 0; k < 4; ++k)
            bb[k] = *reinterpret_cast<const bf16x8*>(kf + (k << 9));
    }

    // ---- A fragments: dense tiled loads (L2/L3-cached plain loads)
    const unsigned short* __restrict__ pa = Rc + (w << 11) + (lane << 3);
#pragma unroll
    for (int k = 0; k < 4; ++k) {
        as[k] = *reinterpret_cast<const bf16x8*>(pa + (k << 9));
        ac[k] = *reinterpret_cast<const bf16x8*>(pa + M_TOT + (k << 9));
    }

    f32x4 acc_s = {0.0f, 0.0f, 0.0f, 0.0f};
    f32x4 acc_c = {0.0f, 0.0f, 0.0f, 0.0f};
#pragma unroll
    for (int k = 0; k < 4; ++k) {
        acc_s = __builtin_amdgcn_mfma_f32_16x16x32_bf16(as[k], bb[k], acc_s, 0, 0, 0);
        acc_c = __builtin_amdgcn_mfma_f32_16x16x32_bf16(ac[k], bb[k], acc_c, 0, 0, 0);
    }
    *reinterpret_cast<f32x4*>(&part[w][0][lane][0]) = acc_s;
    *reinterpret_cast<f32x4*>(&part[w][1][lane][0]) = acc_c;
    __syncthreads();

    // ---- reduce 16 k-partials: cell (c, il), c = half*16 + (ln>>4)*4 + rg
    if (t < 512) {
        const int c = t >> 4, il = t & 15;
        const int half = c >> 4, cl = c & 15;
        const int ln = ((cl >> 2) << 4) | il, rg = cl & 3;
        float s = 0.0f;
#pragma unroll
        for (int q = 0; q < 16; ++q) s += part[q][half][ln][rg];
        coup[c][il] = s;
    }
    __syncthreads();

    // ---- theta update for this block's 256 (b, i)
    if (t < 256) {
        const int b2 = t >> 4;
        const int il = t & 15;
        const float aS = coup[b2][il];
        const float aC = coup[16 + b2][il];
        float nt = th_o + DT * (om_i + scale * (cos_i * aS - sin_i * aC));
        float ws, wc;
        sincosf(nt, &ws, &wc);
        if constexpr (FINAL) {
            th[o_upd] = atan2f(ws, wc);        // final wrap to (-pi, pi]
            // fused coherence: reduce over il (xor masks < 16 stay in group)
#pragma unroll
            for (int m = 1; m < 16; m <<= 1) {
                ws += __shfl_xor(ws, m);
                wc += __shfl_xor(wc, m);
            }
            if (il == 0) {
                atomicAdd(&accum[b2], ws);
                atomicAdd(&accum[16 + b2], wc);
            }
        } else {
            // wrap only shifts by 2*pi*k -> sin/cos unchanged; defer atan2
            th[o_upd] = nt;
            float sn = __shfl_down(ws, 1), cn = __shfl_down(wc, 1);
            if ((il & 1) == 0) {
                *reinterpret_cast<unsigned int*>(Rn + Lr) =
                    (unsigned)f2bf(ws) | ((unsigned)f2bf(sn) << 16);
                *reinterpret_cast<unsigned int*>(Rn + M_TOT + Lr) =
                    (unsigned)f2bf(wc) | ((unsigned)f2bf(cn) << 16);
            }
        }
    }

    if constexpr (FINAL) {
        __syncthreads();
        __threadfence();
        if (t == 0) {
            const unsigned int tk = atomicAdd(ticket, 1u);
            if (tk == NBLK - 1) {              // last block finalizes
                for (int b = 0; b < NB; ++b) {
                    float ss = atomicAdd(&accum[b], 0.0f) * (1.0f / (float)NOSC);
                    float cc = atomicAdd(&accum[16 + b], 0.0f) * (1.0f / (float)NOSC);
                    coh[b] = sqrtf(ss * ss + cc * cc);
                }
            }
        }
    }
}

extern "C" void kernel_launch(void* const* d_in, const int* in_sizes, int n_in,
                              void* d_out, int out_size, void* d_ws, size_t ws_size,
                              hipStream_t stream) {
    const float* theta_in = (const float*)d_in[0];
    const float* Kmat     = (const float*)d_in[1];
    const float* omega    = (const float*)d_in[2];
    const float* kg       = (const float*)d_in[3];
    const float* mod      = (const float*)d_in[4];

    float* th  = (float*)d_out;               // [NB][NOSC] final theta
    float* coh = (float*)d_out + M_TOT;       // [NB]

    unsigned short* Kbt = (unsigned short*)d_ws;                      // 8 MB
    unsigned short* RA  = Kbt + (size_t)NOSC * NOSC;                  // 128 KB
    unsigned short* RB  = RA + 2 * M_TOT;                             // 128 KB
    float* accum = (float*)(RB + 2 * M_TOT);                          // 32 f32
    unsigned int* ticket = (unsigned int*)(accum + 32);

    init_kernel<<<32, 256, 0, stream>>>(theta_in, th, RA, accum, ticket);

    // 10 step dispatches. Parity: s even reads RA writes RB, odd reads RB
    // writes RA (step 9 does no Rn write — coherence fused instead).
    for (int s = 0; s < 10; ++s) {
        const unsigned short* rc = (s & 1) ? RB : RA;
        unsigned short* rn = (s & 1) ? RA : RB;
        if (s == 0)
            step_kernel<true, false><<<NBLK, 1024, 0, stream>>>(
                Kmat, Kbt, rc, rn, omega, kg, mod, th, coh, accum, ticket);
        else if (s < 9)
            step_kernel<false, false><<<NBLK, 1024, 0, stream>>>(
                Kmat, Kbt, rc, rn, omega, kg, mod, th, coh, accum, ticket);
        else
            step_kernel<false, true><<<NBLK, 1024, 0, stream>>>(
                Kmat, Kbt, rc, rn, omega, kg, mod, th, coh, accum, ticket);
    }
}

// Round 22
// 57.785 us; speedup vs baseline: 2.0692x; 1.7472x over previous
//
#include <hip/hip_runtime.h>
#include <math.h>

#define NOSC 2048
#define NB 16
#define DT 0.1f
#define M_TOT (NB * NOSC)    // 32768
#define KTP 2056             // padded LDS K row

typedef __attribute__((ext_vector_type(8))) short bf16x8;
typedef __attribute__((ext_vector_type(4))) float f32x4;

__device__ __forceinline__ unsigned short f2bf(float x) {
    unsigned int u = __float_as_uint(x);
    u += 0x7FFFu + ((u >> 16) & 1u);          // round-to-nearest-even
    return (unsigned short)(u >> 16);
}
__device__ __forceinline__ float bf2f(unsigned short u) {
    return __uint_as_float(((unsigned int)u) << 16);
}

// Fragment-tiled R (verified r15/r19): sin idx(c,j) = (j>>3)*128 + c*8 + (j&7),
// cos at +M_TOT. Wave w's A-fragment chunk k is CONTIGUOUS at
// [w*2048 + k*512 + lane*8 .. +8) shorts.
__device__ __forceinline__ int ridx(int c, int j) {
    return ((j >> 3) << 7) + (c << 3) + (j & 7);
}

// Fragment-tiled K: Kbt offset(bx, w, k, lane) = (((bx*16+w)*4+k)<<9)+(lane<<3).
// Stored once in step 0 from the LDS tile; steps 1-9 read dense 1 KB/wave.
//
// NOTE (r20/r21 lessons, measured):
//  - do NOT fuse init into step 0: every block would sincosf ALL of theta
//    (128x redundant) — measured 59 us for step 0 (r20).
//  - do NOT fuse coherence into step 9 with __threadfence(): 1024-thread
//    device-scope fence = L2 writeback storm (r13 mechanism) — r20/r21 both
//    regressed 43-61 us. Separate 1.5-us coherence dispatch is cheaper.

// ws layout: Kbt[8 MB] | RA (2*M_TOT shorts = 128 KB) | RB (128 KB)

// ---------- init: copy theta, build tiled R0 ----------
__global__ void init_kernel(const float* __restrict__ th_in,
                            float* __restrict__ th,
                            unsigned short* __restrict__ R0) {
    const int idx = blockIdx.x * 256 + threadIdx.x;   // 0..8191
    const int o4 = idx * 4;
    float4 v = *reinterpret_cast<const float4*>(th_in + o4);
    *reinterpret_cast<float4*>(th + o4) = v;
    const int b = o4 >> 11;
    const int j = o4 & (NOSC - 1);                    // j % 4 == 0
    float s0, c0, s1, c1, s2, c2, s3, c3;
    sincosf(v.x, &s0, &c0); sincosf(v.y, &s1, &c1);
    sincosf(v.z, &s2, &c2); sincosf(v.w, &s3, &c3);
    const int L = ridx(b, j);                         // 4 elems stay in-block
    ushort4 us = {f2bf(s0), f2bf(s1), f2bf(s2), f2bf(s3)};
    ushort4 uc = {f2bf(c0), f2bf(c1), f2bf(c2), f2bf(c3)};
    *reinterpret_cast<ushort4*>(R0 + L) = us;
    *reinterpret_cast<ushort4*>(R0 + M_TOT + L) = uc;
}

// ---------- fused step (r11 structure + dense tiled operands) ----------
// 128 blocks x 1024 thr (16 waves). Block owns i in [bx*16, +16), all 16
// batches. Wave w = k-sixteenth: dual 4-deep MFMA chains (sin/cos A-halves
// share B). FIRST: K tile f32->bf16 via LDS; each wave writes its B
// fragments DENSELY to Kbt. Else: B = dense Kbt loads.
template <bool FIRST, bool FINAL>
__global__ __launch_bounds__(1024, 4) void step_kernel(
    const float* __restrict__ Kmat,
    unsigned short* __restrict__ Kbt,
    const unsigned short* __restrict__ Rc,
    unsigned short* __restrict__ Rn,
    const float* __restrict__ omega,
    const float* __restrict__ kg,
    const float* __restrict__ mod,
    float* __restrict__ th)
{
    __shared__ float part[16][2][64][4];     // 32 KB
    __shared__ float coup[32][16];           // 2 KB

    const int t = threadIdx.x;
    const int lane = t & 63;
    const int w = t >> 6;
    const int i0 = blockIdx.x * 16;
    const int rl = lane & 15;
    const int kbase = w * 128 + ((lane >> 4) << 3);

    // ---- prefetch theta-update inputs (waves 0..3)
    float th_o = 0.0f, sin_i = 0.0f, cos_i = 0.0f, om_i = 0.0f;
    size_t o_upd = 0; int Lr = 0;
    if (t < 256) {
        const int b2 = t >> 4;
        const int il = t & 15;
        o_upd = (size_t)b2 * NOSC + i0 + il;
        Lr = ridx(b2, i0 + il);
        th_o = th[o_upd];
        sin_i = bf2f(Rc[Lr]);
        cos_i = bf2f(Rc[M_TOT + Lr]);
        om_i = omega[i0 + il];
    }
    const float scale = kg[0] * (1.0f + mod[0]) * (1.0f / (float)NOSC);

    // ---- B fragments
    bf16x8 as[4], ac[4], bb[4];
    unsigned short* __restrict__ kf =
        Kbt + (((size_t)blockIdx.x * 16 + w) << 11) + (lane << 3);
    if constexpr (FIRST) {
        __shared__ unsigned short Kt[16][KTP];       // 64.25 KB (step 0 only)
        const float4* __restrict__ src =
            reinterpret_cast<const float4*>(Kmat + (size_t)i0 * NOSC);
#pragma unroll
        for (int p = 0; p < 8; ++p) {
            const int q = t + p * 1024;              // float4 index 0..8191
            float4 v = src[q];
            ushort4 u = {f2bf(v.x), f2bf(v.y), f2bf(v.z), f2bf(v.w)};
            *reinterpret_cast<ushort4*>(&Kt[q >> 9][(q & 511) * 4]) = u;
        }
        __syncthreads();
#pragma unroll
        for (int k = 0; k < 4; ++k) {
            bb[k] = *reinterpret_cast<const bf16x8*>(&Kt[rl][kbase + k * 32]);
            // write-through in fragment-tiled order (dense 1 KB/wave stores)
            *reinterpret_cast<bf16x8*>(kf + (k << 9)) = bb[k];
        }
    } else {
#pragma unroll
        for (int k = 0; k < 4; ++k)
            bb[k] = *reinterpret_cast<const bf16x8*>(kf + (k << 9));
    }

    // ---- A fragments: dense tiled loads (L2/L3-cached plain loads)
    const unsigned short* __restrict__ pa = Rc + (w << 11) + (lane << 3);
#pragma unroll
    for (int k = 0; k < 4; ++k) {
        as[k] = *reinterpret_cast<const bf16x8*>(pa + (k << 9));
        ac[k] = *reinterpret_cast<const bf16x8*>(pa + M_TOT + (k << 9));
    }

    f32x4 acc_s = {0.0f, 0.0f, 0.0f, 0.0f};
    f32x4 acc_c = {0.0f, 0.0f, 0.0f, 0.0f};
#pragma unroll
    for (int k = 0; k < 4; ++k) {
        acc_s = __builtin_amdgcn_mfma_f32_16x16x32_bf16(as[k], bb[k], acc_s, 0, 0, 0);
        acc_c = __builtin_amdgcn_mfma_f32_16x16x32_bf16(ac[k], bb[k], acc_c, 0, 0, 0);
    }
    *reinterpret_cast<f32x4*>(&part[w][0][lane][0]) = acc_s;
    *reinterpret_cast<f32x4*>(&part[w][1][lane][0]) = acc_c;
    __syncthreads();

    // ---- reduce 16 k-partials: cell (c, il), c = half*16 + (ln>>4)*4 + rg
    if (t < 512) {
        const int c = t >> 4, il = t & 15;
        const int half = c >> 4, cl = c & 15;
        const int ln = ((cl >> 2) << 4) | il, rg = cl & 3;
        float s = 0.0f;
#pragma unroll
        for (int q = 0; q < 16; ++q) s += part[q][half][ln][rg];
        coup[c][il] = s;
    }
    __syncthreads();

    // ---- theta update for this block's 256 (b, i)
    if (t < 256) {
        const int b2 = t >> 4;
        const int il = t & 15;
        const float aS = coup[b2][il];
        const float aC = coup[16 + b2][il];
        float nt = th_o + DT * (om_i + scale * (cos_i * aS - sin_i * aC));
        float ws, wc;
        sincosf(nt, &ws, &wc);
        // wrap only shifts by 2*pi*k -> sin/cos unchanged; defer atan2
        th[o_upd] = FINAL ? atan2f(ws, wc) : nt;
        float sn = __shfl_down(ws, 1), cn = __shfl_down(wc, 1);
        if ((il & 1) == 0) {
            *reinterpret_cast<unsigned int*>(Rn + Lr) =
                (unsigned)f2bf(ws) | ((unsigned)f2bf(sn) << 16);
            *reinterpret_cast<unsigned int*>(Rn + M_TOT + Lr) =
                (unsigned)f2bf(wc) | ((unsigned)f2bf(cn) << 16);
        }
    }
}

// ---------- coherence from final tiled R ----------
__global__ void coherence_kernel(const unsigned short* __restrict__ R,
                                 float* __restrict__ coh) {
    const int b = blockIdx.x;
    const int t = threadIdx.x;
    const int j0 = t * 8;                    // 256 threads x 8 = 2048
    const int L = ridx(b, j0);               // 8 contiguous shorts
    float ss = 0.0f, sc = 0.0f;
#pragma unroll
    for (int e = 0; e < 8; ++e) {
        ss += bf2f(R[L + e]);
        sc += bf2f(R[M_TOT + L + e]);
    }
    for (int off = 32; off > 0; off >>= 1) {
        ss += __shfl_down(ss, off);
        sc += __shfl_down(sc, off);
    }
    __shared__ float red[8];
    const int w = t >> 6;
    if ((t & 63) == 0) { red[w * 2] = sc; red[w * 2 + 1] = ss; }
    __syncthreads();
    if (t == 0) {
        float tc = 0.0f, ts = 0.0f;
        for (int k = 0; k < 4; ++k) { tc += red[k * 2]; ts += red[k * 2 + 1]; }
        tc /= (float)NOSC;
        ts /= (float)NOSC;
        coh[b] = sqrtf(tc * tc + ts * ts);
    }
}

extern "C" void kernel_launch(void* const* d_in, const int* in_sizes, int n_in,
                              void* d_out, int out_size, void* d_ws, size_t ws_size,
                              hipStream_t stream) {
    const float* theta_in = (const float*)d_in[0];
    const float* Kmat     = (const float*)d_in[1];
    const float* omega    = (const float*)d_in[2];
    const float* kg       = (const float*)d_in[3];
    const float* mod      = (const float*)d_in[4];

    float* th  = (float*)d_out;               // [NB][NOSC] final theta
    float* coh = (float*)d_out + M_TOT;       // [NB]

    unsigned short* Kbt = (unsigned short*)d_ws;                      // 8 MB
    unsigned short* RA  = Kbt + (size_t)NOSC * NOSC;                  // 128 KB
    unsigned short* RB  = RA + 2 * M_TOT;                             // 128 KB

    init_kernel<<<32, 256, 0, stream>>>(theta_in, th, RA);

    for (int s = 0; s < 10; ++s) {
        const unsigned short* rc = (s & 1) ? RB : RA;
        unsigned short* rn = (s & 1) ? RA : RB;
        if (s == 0)
            step_kernel<true, false><<<NOSC / 16, 1024, 0, stream>>>(
                Kmat, Kbt, rc, rn, omega, kg, mod, th);
        else if (s < 9)
            step_kernel<false, false><<<NOSC / 16, 1024, 0, stream>>>(
                Kmat, Kbt, rc, rn, omega, kg, mod, th);
        else
            step_kernel<false, true><<<NOSC / 16, 1024, 0, stream>>>(
                Kmat, Kbt, rc, rn, omega, kg, mod, th);
    }

    // after 10 steps the live buffer is RA (step 9 wrote RA)
    coherence_kernel<<<NB, 256, 0, stream>>>(RA, coh);
}